// Round 6
// baseline (300.184 us; speedup 1.0000x reference)
//
#include <hip/hip_runtime.h>

// ---------------------------------------------------------------------------
// QuaternionLinear == one GEMM: out[M=32768][N=1024] = x[M][K=1024] * W^T + b.
// Round 6: round-5 structure (fused cvt+GEMM, mfma_f32_32x32x16_bf16,
// 256x256 tile, BK=64, 4 phases/K-tile, conflict-free 2-level swizzle,
// v_cvt_pk_bf16_f32, setprio, XCD swizzle) with ONE change: the rh1 (bq)
// global loads are issued at P1 (before the B DMA) instead of P2, so the
// implicit s_waitcnt before every cvt is vmcnt(>=4), never vmcnt(0).
// Round 5's P4 had cvt(bq) waiting on the NEWEST loads -> compiler-forced
// vmcnt(0) -> per-tile full pipeline drain with all 8 waves in lockstep.
// ---------------------------------------------------------------------------

typedef __attribute__((ext_vector_type(8))) short bf16x8;    // 8 bf16 = 4 VGPRs
typedef __attribute__((ext_vector_type(16))) float f32x16;   // 32x32 acc tile

#define M_TOT 32768
#define N_TOT 1024
#define K_TOT 1024
#define BM 256
#define BN 256
#define BK 64
#define NKT (K_TOT / BK)   // 16 K-tiles

__device__ __forceinline__ unsigned short f2bf(float f) {
    union { float f; unsigned int u; } v; v.f = f;
    unsigned int u = v.u;
    u += 0x7fffu + ((u >> 16) & 1u);   // round-to-nearest-even
    return (unsigned short)(u >> 16);
}

// HW packed fp32->bf16 (RNE): no builtin on gfx950, inline asm (T12 recipe).
__device__ __forceinline__ unsigned int pk2(float lo, float hi) {
    unsigned int r;
    asm("v_cvt_pk_bf16_f32 %0, %1, %2" : "=v"(r) : "v"(lo), "v"(hi));
    return r;
}

__device__ __forceinline__ bf16x8 cvt8(float4 a, float4 b) {
    union { unsigned int u[4]; bf16x8 v; } r;
    r.u[0] = pk2(a.x, a.y); r.u[1] = pk2(a.z, a.w);
    r.u[2] = pk2(b.x, b.y); r.u[3] = pk2(b.z, b.w);
    return r.v;
}

// ---- kernel 1: combined quaternion weight matrix, bf16, [N][K] (B^T) ------
__global__ __launch_bounds__(256) void build_w(const float* __restrict__ R,
                                               const float* __restrict__ I,
                                               const float* __restrict__ J,
                                               const float* __restrict__ Kw,
                                               ushort4* __restrict__ Wb) {
    int n = blockIdx.x;          // 0..1023 (output row of W)
    int i = threadIdx.x;         // 0..255  (input quaternion index)
    int o = n >> 2, co = n & 3;
    int base = o * 256 + i;
    float r = R[base], ii = I[base], j = J[base], k = Kw[base];
    float v0, v1, v2, v3;
    if (co == 0)      { v0 = r;  v1 = -ii; v2 = -j;  v3 = -k; }
    else if (co == 1) { v0 = ii; v1 = r;   v2 = k;   v3 = -j; }
    else if (co == 2) { v0 = j;  v1 = -k;  v2 = r;   v3 = ii; }
    else              { v0 = k;  v1 = j;   v2 = -ii; v3 = r;  }
    ushort4 w;
    w.x = f2bf(v0); w.y = f2bf(v1); w.z = f2bf(v2); w.w = f2bf(v3);
    Wb[n * 256 + i] = w;         // coalesced 8B/lane
}

// ---- kernel 2: fused cvt + 256x256-tile MFMA GEMM -------------------------
__device__ __forceinline__ void async_lds16(const void* g, void* l) {
    __builtin_amdgcn_global_load_lds(
        (const __attribute__((address_space(1))) unsigned int*)g,
        (__attribute__((address_space(3))) unsigned int*)l,
        16, 0, 0);
}

// Stage one B half-tile (128 rows x 64 bf16) into 16 subtiles of [16][32]
// bf16.  Storage swizzle (shorts, within-row bits 3-4):
//   cs = c ^ (16 if row&8) ^ (24 if rowgroup&1)
// global_load_lds writes LINEAR, so the swizzle is applied by inverse-
// permuting the per-lane GLOBAL source column.
__device__ __forceinline__ void stage_ht(const unsigned short* __restrict__ G,
                                         int row0, int k0,
                                         unsigned short* ht,
                                         int wave, int lane) {
    int sr = lane >> 2;                                     // subtile row 0..15
    int sc = ((lane & 3) * 8) ^ ((lane & 32) ? 16 : 0)      // row&8 swizzle
           ^ (((wave >> 1) & 1) ? 24 : 0);                  // rowgroup swizzle
#pragma unroll
    for (int j = 0; j < 2; ++j) {
        int si = j * 8 + wave;           // subtile 0..15 (rg parity = (w>>1)&1)
        int rg = si >> 1, cg = si & 1;   // row-group (16 rows), col-group (32)
        async_lds16(G + (size_t)(row0 + rg * 16 + sr) * K_TOT + k0 + cg * 32 + sc,
                    ht + si * 512);
    }
}

__global__ __launch_bounds__(512, 2) void gemm_fused(
        const float* __restrict__ X,            // [M][K] fp32 (activations)
        const unsigned short* __restrict__ B,   // [N][K] bf16 (combined W)
        const float* __restrict__ bias,         // [N]
        float* __restrict__ C) {                // [M][N] fp32
    __shared__ unsigned short smemA[2][2][8192];   // [buf][half][16 subtiles]
    __shared__ unsigned short smemB[2][2][8192];

    const int tid  = threadIdx.x;
    const int wave = tid >> 6;      // 0..7
    const int lane = tid & 63;
    const int wm   = wave & 1;      // wave grid 2(M) x 4(N); wave out: 128x64
    const int wn   = wave >> 1;     // 0..3

    // T1: bijective XCD swizzle (512 workgroups, 512 % 8 == 0)
    int bid = blockIdx.x;
    int wg  = (bid & 7) * 64 + (bid >> 3);
    const int m0 = (wg >> 2) * BM;
    const int n0 = (wg & 3) * BN;   // consecutive wg share the A panel

    // ---- fragment-read lane base (shorts), 32x32x16 operand layout:
    // row/col = lane&31, k = (lane>>5)*8 + j (8 contiguous bf16).
    // Storage col = logical ^ (16 if row&8) ^ (24 if rowgroup&1).
    const int laneRd = (lane & 15) * 32          // row within subtile
                     + ((lane >> 4) & 1) * 1024; // rows 16-31 -> rowgroup+1
    const int klo8 = ((lane >> 5) & 1) << 3;     // k-low 8-elem group (bit3)
    const int rxor = ((lane & 8) << 1)           // row&8 -> XOR 16
                   ^ (((lane >> 4) & 1) ? 24 : 0);  // rowgroup -> XOR 24
    const int kofs[2] = { klo8 ^ rxor, (klo8 ^ rxor) ^ 16 };  // ks even/odd
    const unsigned short* baseA = &smemA[0][wm][0] + laneRd;
    const unsigned short* baseB = &smemB[0][wn >> 1][0] + (wn & 1) * 4096 + laneRd;

    // ---- A staging role: wave = subtile (rg=w>>1, cg=w&1), lane = (row, kc)
    const int srow = (lane >> 2) & 15;
    const int skc  = lane & 3;
    unsigned short* wbase = &smemA[0][0][0] + wave * 512 + srow * 32
                          + ((skc * 8) ^ ((lane & 32) ? 16 : 0)
                                       ^ (((wave >> 1) & 1) ? 24 : 0));
    const float* gBase = X + (size_t)(m0 + (wave >> 1) * 16 + srow) * K_TOT
                       + (wave & 1) * 32 + skc * 8;
    // offsets: +h*131072 floats (half), +rh*65536 floats (row-half), +k0

    f32x16 acc[4][2];
#pragma unroll
    for (int i = 0; i < 4; ++i)
#pragma unroll
        for (int j = 0; j < 2; ++j)
#pragma unroll
            for (int r = 0; r < 16; ++r)
                acc[i][j][r] = 0.f;

    float4 aq0a, aq0b, aq1a, aq1b;   // A(t+2) rh0 (h0,h1): issue P3, write P2
    float4 bq0a, bq0b, bq1a, bq1b;   // A(t+2) rh1 (h0,h1): issue P1, write P4

    // ---- prologue: B(0) via DMA; A tiles 0,1 via reg path; pre-issue A(2) rh0
    stage_ht(B, n0,       0, &smemB[0][0][0], wave, lane);
    stage_ht(B, n0 + 128, 0, &smemB[0][1][0], wave, lane);
#pragma unroll
    for (int tt = 0; tt < 2; ++tt)
#pragma unroll
        for (int rh = 0; rh < 2; ++rh)
#pragma unroll
            for (int h = 0; h < 2; ++h) {
                const float* g = gBase + (size_t)h * 131072 + rh * 65536 + tt * BK;
                float4 a = *(const float4*)g;
                float4 b = *(const float4*)(g + 4);
                *(bf16x8*)(wbase + tt * 16384 + h * 8192 + rh * 4096) = cvt8(a, b);
            }
    aq0a = *(const float4*)(gBase + 2 * BK);
    aq0b = *(const float4*)(gBase + 2 * BK + 4);
    aq1a = *(const float4*)(gBase + 131072 + 2 * BK);
    aq1b = *(const float4*)(gBase + 131072 + 2 * BK + 4);
    asm volatile("s_waitcnt vmcnt(4)" ::: "memory");   // B(0) done; aq in flight
    asm volatile("s_waitcnt lgkmcnt(0)" ::: "memory");
    __builtin_amdgcn_s_barrier();

    bf16x8 af[2][4], bl[4], bh[4];

#pragma unroll 2
    for (int t = 0; t < NKT; ++t) {
        const int c  = t & 1;
        const int cA = c * 16384;   // buffer toggle, shorts

        // ---------- P1: read A rb0-1 + B cb0; issue A(t+2) rh1; stage B(t+1)
        // bq is issued BEFORE the DMAs so every later implicit wait on aq/bq
        // leaves the newest loads in flight (never vmcnt(0) in the loop).
#pragma unroll
        for (int rb = 0; rb < 2; ++rb)
#pragma unroll
            for (int ks = 0; ks < 4; ++ks)
                af[rb][ks] = *(const bf16x8*)(baseA + cA + rb * 2048
                                              + (ks >> 1) * 512 + kofs[ks & 1]);
#pragma unroll
        for (int ks = 0; ks < 4; ++ks)
            bl[ks] = *(const bf16x8*)(baseB + cA + (ks >> 1) * 512 + kofs[ks & 1]);
        if (t + 2 < NKT) {
            const int k2 = (t + 2) * BK;
            bq0a = *(const float4*)(gBase + 65536 + k2);
            bq0b = *(const float4*)(gBase + 65536 + k2 + 4);
            bq1a = *(const float4*)(gBase + 131072 + 65536 + k2);
            bq1b = *(const float4*)(gBase + 131072 + 65536 + k2 + 4);
        }
        if (t + 1 < NKT) {
            stage_ht(B, n0,       (t + 1) * BK, &smemB[c ^ 1][0][0], wave, lane);
            stage_ht(B, n0 + 128, (t + 1) * BK, &smemB[c ^ 1][1][0], wave, lane);
        }
        __builtin_amdgcn_s_barrier();
        asm volatile("s_waitcnt lgkmcnt(0)" ::: "memory");
        __builtin_amdgcn_s_setprio(1);
#pragma unroll
        for (int rb = 0; rb < 2; ++rb)
#pragma unroll
            for (int ks = 0; ks < 4; ++ks)
                acc[rb][0] = __builtin_amdgcn_mfma_f32_32x32x16_bf16(
                    af[rb][ks], bl[ks], acc[rb][0], 0, 0, 0);
        __builtin_amdgcn_s_setprio(0);
        __builtin_amdgcn_s_barrier();

        // ---------- P2: read B cb1; write A(t+2) rh0 (aq: implicit vmcnt>=8)
#pragma unroll
        for (int ks = 0; ks < 4; ++ks)
            bh[ks] = *(const bf16x8*)(baseB + cA + 2048
                                      + (ks >> 1) * 512 + kofs[ks & 1]);
        if (t + 2 < NKT) {
            *(bf16x8*)(wbase + cA)        = cvt8(aq0a, aq0b);   // h0 rh0
            *(bf16x8*)(wbase + cA + 8192) = cvt8(aq1a, aq1b);   // h1 rh0
        }
        __builtin_amdgcn_s_barrier();
        asm volatile("s_waitcnt lgkmcnt(0)" ::: "memory");
        __builtin_amdgcn_s_setprio(1);
#pragma unroll
        for (int rb = 0; rb < 2; ++rb)
#pragma unroll
            for (int ks = 0; ks < 4; ++ks)
                acc[rb][1] = __builtin_amdgcn_mfma_f32_32x32x16_bf16(
                    af[rb][ks], bh[ks], acc[rb][1], 0, 0, 0);
        __builtin_amdgcn_s_setprio(0);
        __builtin_amdgcn_s_barrier();

        // ---------- P3: read A rb2-3; issue A(t+3) rh0 ----------
#pragma unroll
        for (int rb = 0; rb < 2; ++rb)
#pragma unroll
            for (int ks = 0; ks < 4; ++ks)
                af[rb][ks] = *(const bf16x8*)(baseA + cA + (rb + 2) * 2048
                                              + (ks >> 1) * 512 + kofs[ks & 1]);
        if (t + 3 < NKT) {
            const int k3 = (t + 3) * BK;
            aq0a = *(const float4*)(gBase + k3);
            aq0b = *(const float4*)(gBase + k3 + 4);
            aq1a = *(const float4*)(gBase + 131072 + k3);
            aq1b = *(const float4*)(gBase + 131072 + k3 + 4);
        }
        __builtin_amdgcn_s_barrier();
        asm volatile("s_waitcnt lgkmcnt(0)" ::: "memory");
        __builtin_amdgcn_s_setprio(1);
#pragma unroll
        for (int rb = 0; rb < 2; ++rb)
#pragma unroll
            for (int ks = 0; ks < 4; ++ks)
                acc[rb + 2][1] = __builtin_amdgcn_mfma_f32_32x32x16_bf16(
                    af[rb][ks], bh[ks], acc[rb + 2][1], 0, 0, 0);
        __builtin_amdgcn_s_setprio(0);
        __builtin_amdgcn_s_barrier();

        // ---------- P4: MFMA (regs only); write A(t+2) rh1 (bq: implicit
        // vmcnt>=8); publish with counted vmcnt ----------
        __builtin_amdgcn_s_setprio(1);
#pragma unroll
        for (int rb = 0; rb < 2; ++rb)
#pragma unroll
            for (int ks = 0; ks < 4; ++ks)
                acc[rb + 2][0] = __builtin_amdgcn_mfma_f32_32x32x16_bf16(
                    af[rb][ks], bl[ks], acc[rb + 2][0], 0, 0, 0);
        __builtin_amdgcn_s_setprio(0);
        if (t + 2 < NKT) {
            *(bf16x8*)(wbase + cA + 4096)        = cvt8(bq0a, bq0b);  // h0 rh1
            *(bf16x8*)(wbase + cA + 8192 + 4096) = cvt8(bq1a, bq1b);  // h1 rh1
        }
        // publish B(t+1): outstanding = B-DMA(t+1) [4] + aq(t+3) [4 if issued]
        if (t + 3 < NKT) {
            asm volatile("s_waitcnt vmcnt(4)" ::: "memory");   // leave aq live
        } else if (t + 1 < NKT) {
            asm volatile("s_waitcnt vmcnt(0)" ::: "memory");   // tail drain
        }
        asm volatile("s_waitcnt lgkmcnt(0)" ::: "memory");
        __builtin_amdgcn_s_barrier();
    }

    // ---- epilogue: 32x32 C/D layout: col = lane&31,
    // row = (reg&3) + 8*(reg>>2) + 4*(lane>>5)
    const int mbase = m0 + wm * 128 + ((lane >> 5) & 1) * 4;
    const int nbase = n0 + wn * 64 + (lane & 31);
#pragma unroll
    for (int cb = 0; cb < 2; ++cb) {
        int col  = nbase + cb * 32;
        float bv = bias[col];
#pragma unroll
        for (int rb = 0; rb < 4; ++rb) {
            f32x16 v = acc[rb][cb];
#pragma unroll
            for (int r = 0; r < 16; ++r) {
                int row = mbase + rb * 32 + (r & 3) + (r >> 2) * 8;
                C[(size_t)row * N_TOT + col] = v[r] + bv;
            }
        }
    }
}

extern "C" void kernel_launch(void* const* d_in, const int* in_sizes, int n_in,
                              void* d_out, int out_size, void* d_ws, size_t ws_size,
                              hipStream_t stream) {
    const float* x    = (const float*)d_in[0];   // [4, 8192, 1024]
    const float* rw   = (const float*)d_in[1];   // [256, 256]
    const float* iw   = (const float*)d_in[2];
    const float* jw   = (const float*)d_in[3];
    const float* kw   = (const float*)d_in[4];
    const float* bias = (const float*)d_in[5];   // [1024]
    float* out = (float*)d_out;                  // [4, 8192, 1024]

    // workspace: combined W in bf16 (2 MiB) at base
    unsigned short* Wb = (unsigned short*)d_ws;

    // 1) build combined 1024x1024 bf16 weight (B^T layout), 1 block/row
    build_w<<<N_TOT, 256, 0, stream>>>(rw, iw, jw, kw, (ushort4*)Wb);

    // 2) fused cvt+GEMM: 128 x 4 tiles of 256x256, 512 threads (8 waves)
    gemm_fused<<<dim3((M_TOT / BM) * (N_TOT / BN)), 512, 0, stream>>>(
        x, Wb, bias, out);
}